// Round 1
// baseline (178.221 us; speedup 1.0000x reference)
//
#include <hip/hip_runtime.h>

typedef __attribute__((ext_vector_type(8))) short bf16x8;
typedef __attribute__((ext_vector_type(4))) float f32x4;
typedef __attribute__((ext_vector_type(4))) unsigned short u16x4;
typedef __attribute__((ext_vector_type(8))) unsigned short u16x8;

#define DIM 1024
#define SEQ 2048
#define NHEAD 16
#define HDIM 64
#define LOG2E 1.4426950408889634f

__device__ __forceinline__ unsigned short f2bf(float f) {
  union { float f; unsigned u; } v; v.f = f;
  unsigned r = v.u + 0x7fffu + ((v.u >> 16) & 1u);
  return (unsigned short)(r >> 16);
}

__device__ __forceinline__ void gload_lds16(const void* g, void* l) {
  __builtin_amdgcn_global_load_lds(
      (const __attribute__((address_space(1))) void*)g,
      (__attribute__((address_space(3))) void*)l, 16, 0, 0);
}

// ---------------- fp32 -> bf16 conversion ----------------
__global__ void f2bf_kernel(const float* __restrict__ in,
                            unsigned short* __restrict__ out, int n4) {
  int i = blockIdx.x * blockDim.x + threadIdx.x;
  if (i < n4) {
    float4 v = ((const float4*)in)[i];
    u16x4 o;
    o[0] = f2bf(v.x); o[1] = f2bf(v.y); o[2] = f2bf(v.z); o[3] = f2bf(v.w);
    ((u16x4*)out)[i] = o;
  }
}

// ---------------- NT GEMM: C[m,n] = sum_k A[m,k] * B[n,k] ----------------
// A: [M][K] bf16 row-major, B: [N][K] bf16 row-major (nn.Linear weight layout)
// 128x128 tile, BK=64, 4 waves (2x2), global_load_lds w/ pre-swizzled source.
template <bool F32OUT>
__global__ __launch_bounds__(256) void gemm_nt(
    const unsigned short* __restrict__ A,
    const unsigned short* __restrict__ Ball,
    void* __restrict__ Call,
    int K, int N, long long wstride, long long cstride) {
  __shared__ unsigned short As[128 * 64];
  __shared__ unsigned short Bs[128 * 64];
  const int tid = threadIdx.x;
  const int wv = tid >> 6, lane = tid & 63;
  const int g = lane >> 4, l16 = lane & 15;
  const int m0 = blockIdx.y * 128, n0 = blockIdx.x * 128;
  const unsigned short* B = Ball + (long long)blockIdx.z * wstride;
  const int wm = (wv >> 1) * 64, wn = (wv & 1) * 64;
  f32x4 acc[4][4] = {};

  for (int kt = 0; kt < K; kt += 64) {
    __syncthreads();
#pragma unroll
    for (int qq = 0; qq < 4; ++qq) {
      int rbase = wv * 32 + qq * 8;
      int r = rbase + (lane >> 3);
      int cs = ((lane & 7) ^ (r & 7)) * 8;  // pre-swizzled source chunk
      gload_lds16(A + (long long)(m0 + r) * K + kt + cs, &As[rbase * 64]);
      gload_lds16(B + (long long)(n0 + r) * K + kt + cs, &Bs[rbase * 64]);
    }
    __syncthreads();
#pragma unroll
    for (int ks = 0; ks < 2; ++ks) {
      bf16x8 af[4], bfr[4];
      const int cb = ks * 64 + g * 16;
#pragma unroll
      for (int mf = 0; mf < 4; ++mf) {
        int row = wm + mf * 16 + l16;
        af[mf] = *(const bf16x8*)((const char*)As + row * 128 + (cb ^ ((row & 7) << 4)));
      }
#pragma unroll
      for (int nf = 0; nf < 4; ++nf) {
        int row = wn + nf * 16 + l16;
        bfr[nf] = *(const bf16x8*)((const char*)Bs + row * 128 + (cb ^ ((row & 7) << 4)));
      }
#pragma unroll
      for (int mf = 0; mf < 4; ++mf)
#pragma unroll
        for (int nf = 0; nf < 4; ++nf)
          acc[mf][nf] = __builtin_amdgcn_mfma_f32_16x16x32_bf16(
              af[mf], bfr[nf], acc[mf][nf], 0, 0, 0);
    }
  }

  // epilogue: D layout col = lane&15, row = (lane>>4)*4 + reg
#pragma unroll
  for (int mf = 0; mf < 4; ++mf)
#pragma unroll
    for (int nf = 0; nf < 4; ++nf)
#pragma unroll
      for (int r = 0; r < 4; ++r) {
        long long m = m0 + wm + mf * 16 + g * 4 + r;
        long long n = n0 + wn + nf * 16 + l16;
        float v = acc[mf][nf][r];
        if (F32OUT)
          ((float*)Call)[(long long)blockIdx.z * cstride + m * N + n] = v;
        else
          ((unsigned short*)Call)[(long long)blockIdx.z * cstride + m * N + n] = f2bf(v);
      }
}

// ---------------- flash attention (causal) ----------------
// grid: (S/128, H, B); 4 waves, each owns 32 q-rows. KBLK=64.
// Swapped QK^T: ST[key,q] = mfma(K_frag, Q_frag) so lane&15 indexes q.
// PV swapped:   OT[d,q]  = mfma(VT_frag, PT_frag).
__global__ __launch_bounds__(256) void attn_kernel(
    const unsigned short* __restrict__ Qg,
    const unsigned short* __restrict__ Kg,
    const unsigned short* __restrict__ Vg,
    unsigned short* __restrict__ Og) {
  __shared__ unsigned short Ks[64 * 64];
  __shared__ unsigned short Vt[64 * 64];   // transposed: [d][kk]
  __shared__ unsigned short Ps[4][32 * 64];  // per-wave P (rows=q, cols=kk)

  const int tid = threadIdx.x;
  const int wv = tid >> 6, lane = tid & 63;
  const int g = lane >> 4, l16 = lane & 15;
  const int h = blockIdx.y, b = blockIdx.z;
  const int q0 = blockIdx.x * 128;
  const long long bh = (long long)b * SEQ * DIM + h * HDIM;

  // Q fragments (B-operand): qf[nf][ks][j] = Q[q0+wv*32+nf*16+l16][ks*32+g*8+j]
  bf16x8 qf[2][2];
#pragma unroll
  for (int nf = 0; nf < 2; ++nf)
#pragma unroll
    for (int ks = 0; ks < 2; ++ks) {
      int q = q0 + wv * 32 + nf * 16 + l16;
      qf[nf][ks] = *(const bf16x8*)(Qg + bh + (long long)q * DIM + ks * 32 + g * 8);
    }

  f32x4 acc[4][2] = {};            // [mf over d][nf over q]
  float m_run[2] = {-1e30f, -1e30f};
  float l_run[2] = {0.f, 0.f};

  const int ktiles = (q0 + 128) / 64;
  for (int t = 0; t < ktiles; ++t) {
    const int kv0 = t * 64;
    __syncthreads();
    // --- stage K (global_load_lds, pre-swizzled source) ---
#pragma unroll
    for (int c = 0; c < 2; ++c) {
      int rbase = wv * 16 + c * 8;
      int r = rbase + (lane >> 3);
      int cs = ((lane & 7) ^ (r & 7)) * 8;
      gload_lds16(Kg + bh + (long long)(kv0 + r) * DIM + cs, &Ks[rbase * 64]);
    }
    // --- stage V transposed: Vt[d][kk], swizzled ---
    {
      int kk = tid & 63, c2 = tid >> 6;
#pragma unroll
      for (int cc = 2 * c2; cc <= 2 * c2 + 1; ++cc) {
        u16x8 v = *(const u16x8*)(Vg + bh + (long long)(kv0 + kk) * DIM + cc * 8);
#pragma unroll
        for (int j = 0; j < 8; ++j) {
          int d = cc * 8 + j;
          int byte = d * 128 + ((kk * 2) ^ ((d & 7) << 4));
          *(unsigned short*)((char*)Vt + byte) = v[j];
        }
      }
    }
    __syncthreads();

    // --- QK^T (swapped): s[mf][nf] = ST[key= mf*16+g*4+r][q = nf*16+l16] ---
    f32x4 s[4][2] = {};
#pragma unroll
    for (int ks = 0; ks < 2; ++ks) {
      bf16x8 kf[4];
      const int cb = ks * 64 + g * 16;
#pragma unroll
      for (int mf = 0; mf < 4; ++mf) {
        int row = mf * 16 + l16;
        kf[mf] = *(const bf16x8*)((const char*)Ks + row * 128 + (cb ^ ((row & 7) << 4)));
      }
#pragma unroll
      for (int mf = 0; mf < 4; ++mf)
#pragma unroll
        for (int nf = 0; nf < 2; ++nf)
          s[mf][nf] = __builtin_amdgcn_mfma_f32_16x16x32_bf16(
              kf[mf], qf[nf][ks], s[mf][nf], 0, 0, 0);
    }

    // --- online softmax per q (q = col = lane&15) ---
#pragma unroll
    for (int nf = 0; nf < 2; ++nf) {
      const int q = q0 + wv * 32 + nf * 16 + l16;
      float pm = -1e30f;
#pragma unroll
      for (int mf = 0; mf < 4; ++mf)
#pragma unroll
        for (int r = 0; r < 4; ++r) {
          int key = kv0 + mf * 16 + g * 4 + r;
          float val = s[mf][nf][r] * 0.125f;
          val = (key <= q) ? val : -1e30f;
          s[mf][nf][r] = val;
          pm = fmaxf(pm, val);
        }
      pm = fmaxf(pm, __shfl_xor(pm, 16));
      pm = fmaxf(pm, __shfl_xor(pm, 32));
      float m_new = fmaxf(m_run[nf], pm);
      float rs = exp2f((m_run[nf] - m_new) * LOG2E);
      float l_add = 0.f;
#pragma unroll
      for (int mf = 0; mf < 4; ++mf) {
        u16x4 pk;
#pragma unroll
        for (int r = 0; r < 4; ++r) {
          float p = exp2f((s[mf][nf][r] - m_new) * LOG2E);
          l_add += p;
          pk[r] = f2bf(p);
        }
        int row = nf * 16 + l16;
        int byte = row * 128 + ((mf * 32 + g * 8) ^ ((row & 7) << 4));
        *(u16x4*)((char*)&Ps[wv][0] + byte) = pk;
      }
      l_add += __shfl_xor(l_add, 16);
      l_add += __shfl_xor(l_add, 32);
      l_run[nf] = l_run[nf] * rs + l_add;
      m_run[nf] = m_new;
#pragma unroll
      for (int mf = 0; mf < 4; ++mf) {
#pragma unroll
        for (int r = 0; r < 4; ++r) acc[mf][nf][r] *= rs;
      }
    }

    // --- PV (swapped): acc += VT · PT ---
#pragma unroll
    for (int ks = 0; ks < 2; ++ks) {
      bf16x8 vf[4], pf[2];
      const int cb = ks * 64 + g * 16;
#pragma unroll
      for (int mf = 0; mf < 4; ++mf) {
        int row = mf * 16 + l16;  // d
        vf[mf] = *(const bf16x8*)((const char*)Vt + row * 128 + (cb ^ ((row & 7) << 4)));
      }
#pragma unroll
      for (int nf = 0; nf < 2; ++nf) {
        int row = nf * 16 + l16;  // q local
        pf[nf] = *(const bf16x8*)((const char*)&Ps[wv][0] + row * 128 + (cb ^ ((row & 7) << 4)));
      }
#pragma unroll
      for (int mf = 0; mf < 4; ++mf)
#pragma unroll
        for (int nf = 0; nf < 2; ++nf)
          acc[mf][nf] = __builtin_amdgcn_mfma_f32_16x16x32_bf16(
              vf[mf], pf[nf], acc[mf][nf], 0, 0, 0);
    }
  }

  // --- epilogue: out[b, q, h*64 + d] = acc / l ---
#pragma unroll
  for (int nf = 0; nf < 2; ++nf) {
    float inv_l = 1.0f / l_run[nf];
    int q = q0 + wv * 32 + nf * 16 + l16;
#pragma unroll
    for (int mf = 0; mf < 4; ++mf) {
      int d0 = mf * 16 + g * 4;
      u16x4 o;
#pragma unroll
      for (int r = 0; r < 4; ++r) o[r] = f2bf(acc[mf][nf][r] * inv_l);
      *(u16x4*)(Og + (long long)(b * SEQ + q) * DIM + h * HDIM + d0) = o;
    }
  }
}

// ---------------- launcher ----------------
extern "C" void kernel_launch(void* const* d_in, const int* in_sizes, int n_in,
                              void* d_out, int out_size, void* d_ws, size_t ws_size,
                              hipStream_t stream) {
  const float* x   = (const float*)d_in[0];
  // d_in[1] = mask (causal, hardcoded in kernel)
  const float* wq  = (const float*)d_in[2];
  const float* wk  = (const float*)d_in[3];
  const float* wv_ = (const float*)d_in[4];
  const float* wo  = (const float*)d_in[5];

  unsigned short* xb  = (unsigned short*)d_ws;            // [4096][1024]
  unsigned short* wb  = xb + (size_t)4096 * 1024;         // [4][1024][1024] q,k,v,o
  unsigned short* qkv = wb + (size_t)4 * 1024 * 1024;     // [3][4096][1024]
  unsigned short* ao  = qkv + (size_t)3 * 4096 * 1024;    // [4096][1024]

  f2bf_kernel<<<4096, 256, 0, stream>>>(x, xb, 1048576);
  f2bf_kernel<<<1024, 256, 0, stream>>>(wq, wb, 262144);
  f2bf_kernel<<<1024, 256, 0, stream>>>(wk, wb + 1048576, 262144);
  f2bf_kernel<<<1024, 256, 0, stream>>>(wv_, wb + 2097152, 262144);
  f2bf_kernel<<<1024, 256, 0, stream>>>(wo, wb + 3145728, 262144);

  // QKV projections: one launch, z selects weight/output
  gemm_nt<false><<<dim3(8, 32, 3), 256, 0, stream>>>(
      xb, wb, qkv, 1024, 1024, 1048576LL, 4194304LL);

  attn_kernel<<<dim3(16, 16, 2), 256, 0, stream>>>(
      qkv, qkv + 4194304, qkv + 2 * 4194304, ao);

  // output projection -> fp32 d_out
  gemm_nt<true><<<dim3(8, 32, 1), 256, 0, stream>>>(
      ao, wb + 3145728, d_out, 1024, 1024, 0LL, 0LL);
}